// Round 1
// baseline (3274.703 us; speedup 1.0000x reference)
//
#include <hip/hip_runtime.h>
#include <hip/hip_bf16.h>

// Problem: PointCloudNetPersistencePrediction
// B=4 clouds x K=4 alphas = 16 pairs; N=2048, d=3.
// Per pair: W = thresh(exp(-pdist2/10), 0.1); deg = rowsum(W); P = 0.5(I + W/deg).
// Bank1: P^t X at t=1,2,4,8,16 (width 3). U = |wavelets| (first 12 cols needed).
// Bank2: P^t U at t=1,2,4,8,16 (width 12). Output: mean over N of 48 features, [4,192] f32.

#define NN 2048
#define NPAIR 16
#define S4  (NPAIR * NN * 4)    // stride-4 buffer elems (float)
#define S12 (NPAIR * NN * 12)   // stride-12 buffer elems (float)

// ---- init: Xs[p][i][0..2] = pc[b][i][c]*alpha[k][c], col3 = 0 ----
__global__ __launch_bounds__(256) void init_k(const float* __restrict__ pc,
                                              const float* __restrict__ alphas,
                                              float* __restrict__ Xs) {
    int gid = blockIdx.x * 256 + threadIdx.x;      // 0 .. 16*2048-1
    if (gid >= NPAIR * NN) return;
    int p = gid >> 11;          // pair
    int i = gid & (NN - 1);
    int b = p >> 2, k = p & 3;
    const float* pcr = pc + ((size_t)b * NN + i) * 3;
    const float* al  = alphas + k * 3;
    float4 o;
    o.x = pcr[0] * al[0];
    o.y = pcr[1] * al[1];
    o.z = pcr[2] * al[2];
    o.w = 0.0f;
    ((float4*)Xs)[gid] = o;
}

__device__ __forceinline__ float wfun(float4 xi, float4 xj) {
    float dx = xi.x - xj.x, dy = xi.y - xj.y, dz = xi.z - xj.z;
    float d2 = dx * dx + dy * dy + dz * dz;
    float w = __expf(-0.1f * d2);
    return (w < 0.1f) ? 0.0f : w;
}

// ---- deg: ihd[p][i] = 0.5 / sum_j w(i,j) ----
__global__ __launch_bounds__(256) void deg_k(const float* __restrict__ Xs,
                                             float* __restrict__ ihd) {
    const int p    = blockIdx.y;
    const int lane = threadIdx.x & 63;
    const int wv   = threadIdx.x >> 6;            // 0..3, j-quarter
    const int row  = blockIdx.x * 64 + lane;
    const float4* Xp = (const float4*)(Xs + (size_t)p * NN * 4);
    float4 xi = Xp[row];
    float s = 0.0f;
    const int j0 = wv * 512;
    for (int j = j0; j < j0 + 512; ++j) s += wfun(xi, Xp[j]);
    __shared__ float red[4][64];
    red[wv][lane] = s;
    __syncthreads();
    if (wv == 0) {
        float deg = red[0][lane] + red[1][lane] + red[2][lane] + red[3][lane];
        ihd[p * NN + row] = 0.5f / deg;
    }
}

// ---- fused apply: out = 0.5*cur + ihd[i] * (W @ cur), width = 4*NV4 ----
template<int NV4>
__global__ __launch_bounds__(256) void apply_k(const float* __restrict__ Xs,
                                               const float* __restrict__ ihd,
                                               const float* __restrict__ cur,
                                               float* __restrict__ out) {
    const int p    = blockIdx.y;
    const int lane = threadIdx.x & 63;
    const int wv   = threadIdx.x >> 6;            // j-quarter
    const int row  = blockIdx.x * 64 + lane;
    const float4* Xp   = (const float4*)(Xs + (size_t)p * NN * 4);
    const float4* curp = (const float4*)(cur + (size_t)p * NN * NV4 * 4);
    float4 xi = Xp[row];
    float acc[NV4 * 4];
#pragma unroll
    for (int c = 0; c < NV4 * 4; ++c) acc[c] = 0.0f;
    const int j0 = wv * 512;
    for (int j = j0; j < j0 + 512; ++j) {
        float w = wfun(xi, Xp[j]);
#pragma unroll
        for (int v = 0; v < NV4; ++v) {
            float4 cv = curp[j * NV4 + v];
            acc[v * 4 + 0] += w * cv.x;
            acc[v * 4 + 1] += w * cv.y;
            acc[v * 4 + 2] += w * cv.z;
            acc[v * 4 + 3] += w * cv.w;
        }
    }
    __shared__ float red[4][64][NV4 * 4];
#pragma unroll
    for (int c = 0; c < NV4 * 4; ++c) red[wv][lane][c] = acc[c];
    __syncthreads();
    if (wv == 0) {
        float ih = ihd[p * NN + row];
        float4* outp = (float4*)(out + (size_t)p * NN * NV4 * 4);
#pragma unroll
        for (int v = 0; v < NV4; ++v) {
            float4 cv = curp[row * NV4 + v];
            float4 o;
            o.x = 0.5f * cv.x + ih * (red[0][lane][v*4+0] + red[1][lane][v*4+0] + red[2][lane][v*4+0] + red[3][lane][v*4+0]);
            o.y = 0.5f * cv.y + ih * (red[0][lane][v*4+1] + red[1][lane][v*4+1] + red[2][lane][v*4+1] + red[3][lane][v*4+1]);
            o.z = 0.5f * cv.z + ih * (red[0][lane][v*4+2] + red[1][lane][v*4+2] + red[2][lane][v*4+2] + red[3][lane][v*4+2]);
            o.w = 0.5f * cv.w + ih * (red[0][lane][v*4+3] + red[1][lane][v*4+3] + red[2][lane][v*4+3] + red[3][lane][v*4+3]);
            outp[row * NV4 + v] = o;
        }
    }
}

// ---- build U (first 12 cols of first-order scattering): |psi_0..psi_3 x| ----
__global__ __launch_bounds__(256) void buildU_k(const float* __restrict__ Xs,
                                                const float* __restrict__ L1b,
                                                float* __restrict__ U) {
    int gid = blockIdx.x * 256 + threadIdx.x;     // p*2048+i
    if (gid >= NPAIR * NN) return;
    float4 xr = ((const float4*)Xs)[gid];
    float prev0 = xr.x, prev1 = xr.y, prev2 = xr.z;
    float* urow = U + (size_t)gid * 12;
#pragma unroll
    for (int j = 0; j < 4; ++j) {
        float4 nx = ((const float4*)(L1b + (size_t)j * S4))[gid];
        urow[3 * j + 0] = fabsf(prev0 - nx.x);
        urow[3 * j + 1] = fabsf(prev1 - nx.y);
        urow[3 * j + 2] = fabsf(prev2 - nx.z);
        prev0 = nx.x; prev1 = nx.y; prev2 = nx.z;
    }
}

// ---- final mean over N of 48 features ----
__global__ __launch_bounds__(64) void reduce_k(const float* __restrict__ Xs,
                                               const float* __restrict__ L1b,
                                               const float* __restrict__ L2b,
                                               float* __restrict__ out) {
    const int f = blockIdx.x;    // 0..47
    const int p = blockIdx.y;    // 0..15
    const int lane = threadIdx.x;
    float s = 0.0f;
    for (int r = lane; r < NN; r += 64) {
        int pi = p * NN + r;
        float v;
        if (f < 3) {
            v = L1b[(size_t)4 * S4 + (size_t)pi * 4 + f];            // low = P^16 F
        } else if (f < 18) {
            int j = (f - 3) / 3, c = (f - 3) % 3;
            float a = (j == 0) ? Xs[(size_t)pi * 4 + c]
                               : L1b[(size_t)(j - 1) * S4 + (size_t)pi * 4 + c];
            float b = L1b[(size_t)j * S4 + (size_t)pi * 4 + c];
            v = fabsf(a - b);
        } else {
            int g = f - 18;
            int j2, c;
            if (g < 3)       { j2 = 1; c = g; }
            else if (g < 9)  { j2 = 2; c = g - 3; }
            else if (g < 18) { j2 = 3; c = g - 9; }
            else             { j2 = 4; c = g - 18; }
            size_t idx = (size_t)pi * 12 + c;
            float a = L2b[(size_t)(j2 - 1) * S12 + idx];
            float b = L2b[(size_t)j2 * S12 + idx];
            v = fabsf(a - b);
        }
        s += v;
    }
#pragma unroll
    for (int off = 32; off > 0; off >>= 1) s += __shfl_down(s, off, 64);
    if (lane == 0) out[p * 48 + f] = s * (1.0f / 2048.0f);
}

extern "C" void kernel_launch(void* const* d_in, const int* in_sizes, int n_in,
                              void* d_out, int out_size, void* d_ws, size_t ws_size,
                              hipStream_t stream) {
    const float* pc     = (const float*)d_in[0];  // [4,2048,3]
    const float* alphas = (const float*)d_in[1];  // [4,3]
    float* outp = (float*)d_out;                  // [4,192]

    float* w = (float*)d_ws;
    float* Xs  = w;               w += S4;        // [16][2048][4]
    float* ihd = w;               w += NPAIR * NN;
    float* sA  = w;               w += S4;
    float* sB  = w;               w += S4;
    float* L1b = w;               w += 5 * S4;    // P^{1,2,4,8,16} X
    float* U   = w;               w += S12;
    float* sC  = w;               w += S12;
    float* sD  = w;               w += S12;
    float* L2b = w;               w += 5 * S12;   // P^{1,2,4,8,16} U

    dim3 gridRows(NN / 64, NPAIR);

    init_k<<<dim3((NPAIR * NN) / 256), 256, 0, stream>>>(pc, alphas, Xs);
    deg_k<<<gridRows, 256, 0, stream>>>(Xs, ihd);

    // bank 1: width 3 (stride 4)
    {
        const float* cur = Xs;
        int slot = 0;
        for (int step = 1; step <= 16; ++step) {
            bool sv = (step == 1 || step == 2 || step == 4 || step == 8 || step == 16);
            float* o = sv ? (L1b + (size_t)slot * S4)
                          : ((cur == sA) ? sB : sA);
            apply_k<1><<<gridRows, 256, 0, stream>>>(Xs, ihd, cur, o);
            if (sv) ++slot;
            cur = o;
        }
    }

    buildU_k<<<dim3((NPAIR * NN) / 256), 256, 0, stream>>>(Xs, L1b, U);

    // bank 2: width 12 (stride 12)
    {
        const float* cur = U;
        int slot = 0;
        for (int step = 1; step <= 16; ++step) {
            bool sv = (step == 1 || step == 2 || step == 4 || step == 8 || step == 16);
            float* o = sv ? (L2b + (size_t)slot * S12)
                          : ((cur == sC) ? sD : sC);
            apply_k<3><<<gridRows, 256, 0, stream>>>(Xs, ihd, cur, o);
            if (sv) ++slot;
            cur = o;
        }
    }

    reduce_k<<<dim3(48, NPAIR), 64, 0, stream>>>(Xs, L1b, L2b, outp);
}

// Round 2
// 2898.554 us; speedup vs baseline: 1.1298x; 1.1298x over previous
//
#include <hip/hip_runtime.h>
#include <hip/hip_bf16.h>

// PointCloudNetPersistencePrediction — round 2: occupancy + VALU-count fix.
// 16 pairs (B=4 x K=4), N=2048, d=3. Fused W-recompute diffusion.
// Round1: VALUBusy 21%, Occupancy 22% (grid-limited: 2 waves/SIMD). Fix:
// 1024-thread blocks, 16-way j-split -> 8 waves/SIMD; Gram-form wfun with
// precomputed -0.1*log2e*|x|^2 in Xs.w -> exp2 directly (saves ~15% VALU).

#define NN 2048
#define NPAIR 16
#define S4  (NPAIR * NN * 4)    // stride-4 buffer elems (float)
#define S12 (NPAIR * NN * 12)   // stride-12 buffer elems (float)

#define C2F 0.28853900817779268f   //  0.2 * log2(e)
#define CWF -0.14426950408889634f  // -0.1 * log2(e)

// ---- init: Xs[p][i] = {x,y,z, -0.1*log2e*|x|^2} ----
__global__ __launch_bounds__(256) void init_k(const float* __restrict__ pc,
                                              const float* __restrict__ alphas,
                                              float* __restrict__ Xs) {
    int gid = blockIdx.x * 256 + threadIdx.x;      // 0 .. 16*2048-1
    if (gid >= NPAIR * NN) return;
    int p = gid >> 11;
    int i = gid & (NN - 1);
    int b = p >> 2, k = p & 3;
    const float* pcr = pc + ((size_t)b * NN + i) * 3;
    const float* al  = alphas + k * 3;
    float x = pcr[0] * al[0];
    float y = pcr[1] * al[1];
    float z = pcr[2] * al[2];
    float4 o;
    o.x = x; o.y = y; o.z = z;
    o.w = CWF * (x * x + y * y + z * z);
    ((float4*)Xs)[gid] = o;
}

// w(i,j) = exp(-0.1*(|xi|^2+|xj|^2-2 xi.xj)) = exp2(xi.w + xj.w + C2F*dot)
__device__ __forceinline__ float wfun(float4 xi, float4 xj) {
    float dot = xi.x * xj.x + xi.y * xj.y + xi.z * xj.z;
    float arg = (xi.w + xj.w) + C2F * dot;
    float w = __builtin_amdgcn_exp2f(arg);
    return (w < 0.1f) ? 0.0f : w;
}

// ---- deg: ihd[p][i] = 0.5 / sum_j w(i,j).  1024 thr, 16-way j-split ----
__global__ __launch_bounds__(1024, 8) void deg_k(const float* __restrict__ Xs,
                                                 float* __restrict__ ihd) {
    const int p    = blockIdx.y;
    const int tid  = threadIdx.x;
    const int lane = tid & 63;
    const int wv   = tid >> 6;                     // 0..15 j-chunk
    const int row  = blockIdx.x * 64 + lane;
    const float4* Xp = (const float4*)(Xs + (size_t)p * NN * 4);
    float4 xi = Xp[row];
    float s = 0.0f;
    const int j0 = wv * 128;
#pragma unroll 2
    for (int j = j0; j < j0 + 128; ++j) s += wfun(xi, Xp[j]);
    __shared__ float red[16][64];
    red[wv][lane] = s;
    __syncthreads();
    if (tid < 64) {
        float d = 0.0f;
#pragma unroll
        for (int w = 0; w < 16; ++w) d += red[w][tid];
        ihd[p * NN + blockIdx.x * 64 + tid] = 0.5f / d;
    }
}

// ---- fused apply: out = 0.5*cur + ihd[i]*(W@cur), width = 4*NV4 ----
// 1024 threads = 16 waves, each wave owns a 128-wide j-chunk for 64 rows.
template<int NV4>
__global__ __launch_bounds__(1024, 8) void apply_k(const float* __restrict__ Xs,
                                                   const float* __restrict__ ihd,
                                                   const float* __restrict__ cur,
                                                   float* __restrict__ out) {
    const int p    = blockIdx.y;
    const int tid  = threadIdx.x;
    const int lane = tid & 63;
    const int wv   = tid >> 6;                     // 0..15 j-chunk
    const int row  = blockIdx.x * 64 + lane;
    const float4* Xp   = (const float4*)(Xs + (size_t)p * NN * 4);
    const float4* curp = (const float4*)(cur + (size_t)p * NN * NV4 * 4);
    float4 xi = Xp[row];
    float acc[NV4 * 4];
#pragma unroll
    for (int c = 0; c < NV4 * 4; ++c) acc[c] = 0.0f;
    const int j0 = wv * 128;
#pragma unroll 2
    for (int j = j0; j < j0 + 128; ++j) {
        float w = wfun(xi, Xp[j]);
#pragma unroll
        for (int v = 0; v < NV4; ++v) {
            float4 cv = curp[j * NV4 + v];
            acc[v * 4 + 0] += w * cv.x;
            acc[v * 4 + 1] += w * cv.y;
            acc[v * 4 + 2] += w * cv.z;
            acc[v * 4 + 3] += w * cv.w;
        }
    }
    __shared__ float red[16][64][NV4 * 4];
#pragma unroll
    for (int c = 0; c < NV4 * 4; ++c) red[wv][lane][c] = acc[c];
    __syncthreads();
    // cooperative epilogue: 64*W values, consecutive threads -> consecutive addrs
    constexpr int W = NV4 * 4;
    const float* curf = cur + (size_t)p * NN * W;
    float*       outf = out + (size_t)p * NN * W;
    const float* ihp  = ihd + p * NN;
    for (int v = tid; v < 64 * W; v += 1024) {
        int r = v / W, c = v - r * W;
        float s = 0.0f;
#pragma unroll
        for (int w = 0; w < 16; ++w) s += red[w][r][c];
        int row2 = blockIdx.x * 64 + r;
        outf[(size_t)row2 * W + c] = 0.5f * curf[(size_t)row2 * W + c] + ihp[row2] * s;
    }
}

// ---- build U (first 12 cols of first-order scattering): |psi_0..psi_3 x| ----
__global__ __launch_bounds__(256) void buildU_k(const float* __restrict__ Xs,
                                                const float* __restrict__ L1b,
                                                float* __restrict__ U) {
    int gid = blockIdx.x * 256 + threadIdx.x;     // p*2048+i
    if (gid >= NPAIR * NN) return;
    float4 xr = ((const float4*)Xs)[gid];
    float prev0 = xr.x, prev1 = xr.y, prev2 = xr.z;
    float* urow = U + (size_t)gid * 12;
#pragma unroll
    for (int j = 0; j < 4; ++j) {
        float4 nx = ((const float4*)(L1b + (size_t)j * S4))[gid];
        urow[3 * j + 0] = fabsf(prev0 - nx.x);
        urow[3 * j + 1] = fabsf(prev1 - nx.y);
        urow[3 * j + 2] = fabsf(prev2 - nx.z);
        prev0 = nx.x; prev1 = nx.y; prev2 = nx.z;
    }
}

// ---- final mean over N of 48 features ----
__global__ __launch_bounds__(64) void reduce_k(const float* __restrict__ Xs,
                                               const float* __restrict__ L1b,
                                               const float* __restrict__ L2b,
                                               float* __restrict__ out) {
    const int f = blockIdx.x;    // 0..47
    const int p = blockIdx.y;    // 0..15
    const int lane = threadIdx.x;
    float s = 0.0f;
    for (int r = lane; r < NN; r += 64) {
        int pi = p * NN + r;
        float v;
        if (f < 3) {
            v = L1b[(size_t)4 * S4 + (size_t)pi * 4 + f];            // low = P^16 F
        } else if (f < 18) {
            int j = (f - 3) / 3, c = (f - 3) % 3;
            float a = (j == 0) ? Xs[(size_t)pi * 4 + c]
                               : L1b[(size_t)(j - 1) * S4 + (size_t)pi * 4 + c];
            float b = L1b[(size_t)j * S4 + (size_t)pi * 4 + c];
            v = fabsf(a - b);
        } else {
            int g = f - 18;
            int j2, c;
            if (g < 3)       { j2 = 1; c = g; }
            else if (g < 9)  { j2 = 2; c = g - 3; }
            else if (g < 18) { j2 = 3; c = g - 9; }
            else             { j2 = 4; c = g - 18; }
            size_t idx = (size_t)pi * 12 + c;
            float a = L2b[(size_t)(j2 - 1) * S12 + idx];
            float b = L2b[(size_t)j2 * S12 + idx];
            v = fabsf(a - b);
        }
        s += v;
    }
#pragma unroll
    for (int off = 32; off > 0; off >>= 1) s += __shfl_down(s, off, 64);
    if (lane == 0) out[p * 48 + f] = s * (1.0f / 2048.0f);
}

extern "C" void kernel_launch(void* const* d_in, const int* in_sizes, int n_in,
                              void* d_out, int out_size, void* d_ws, size_t ws_size,
                              hipStream_t stream) {
    const float* pc     = (const float*)d_in[0];  // [4,2048,3]
    const float* alphas = (const float*)d_in[1];  // [4,3]
    float* outp = (float*)d_out;                  // [4,192]

    float* w = (float*)d_ws;
    float* Xs  = w;               w += S4;        // [16][2048][4]
    float* ihd = w;               w += NPAIR * NN;
    float* sA  = w;               w += S4;
    float* sB  = w;               w += S4;
    float* L1b = w;               w += 5 * S4;    // P^{1,2,4,8,16} X
    float* U   = w;               w += S12;
    float* sC  = w;               w += S12;
    float* sD  = w;               w += S12;
    float* L2b = w;               w += 5 * S12;   // P^{1,2,4,8,16} U

    dim3 gridRows(NN / 64, NPAIR);

    init_k<<<dim3((NPAIR * NN) / 256), 256, 0, stream>>>(pc, alphas, Xs);
    deg_k<<<gridRows, 1024, 0, stream>>>(Xs, ihd);

    // bank 1: width 3 (stride 4)
    {
        const float* cur = Xs;
        int slot = 0;
        for (int step = 1; step <= 16; ++step) {
            bool sv = (step == 1 || step == 2 || step == 4 || step == 8 || step == 16);
            float* o = sv ? (L1b + (size_t)slot * S4)
                          : ((cur == sA) ? sB : sA);
            apply_k<1><<<gridRows, 1024, 0, stream>>>(Xs, ihd, cur, o);
            if (sv) ++slot;
            cur = o;
        }
    }

    buildU_k<<<dim3((NPAIR * NN) / 256), 256, 0, stream>>>(Xs, L1b, U);

    // bank 2: width 12 (stride 12)
    {
        const float* cur = U;
        int slot = 0;
        for (int step = 1; step <= 16; ++step) {
            bool sv = (step == 1 || step == 2 || step == 4 || step == 8 || step == 16);
            float* o = sv ? (L2b + (size_t)slot * S12)
                          : ((cur == sC) ? sD : sC);
            apply_k<3><<<gridRows, 1024, 0, stream>>>(Xs, ihd, cur, o);
            if (sv) ++slot;
            cur = o;
        }
    }

    reduce_k<<<dim3(48, NPAIR), 64, 0, stream>>>(Xs, L1b, L2b, outp);
}

// Round 3
// 1110.035 us; speedup vs baseline: 2.9501x; 2.6112x over previous
//
#include <hip/hip_runtime.h>
#include <hip/hip_bf16.h>

// PointCloudNetPersistencePrediction — round 3: kill uniform-address VMEM.
// R2 post-mortem: VALUBusy 23% @ 72% occupancy -> inner loop bound by 4
// wave-uniform global loads per j (full TA cost for a 16B broadcast).
// Fix: per-wave LDS staging tiles (1 coalesced f4 load/lane/tile), uniform
// ds_read_b128 broadcasts (free), 2 rows/lane register tiling.

#define NN 2048
#define NPAIR 16
#define S4  (NPAIR * NN * 4)
#define S12 (NPAIR * NN * 12)

#define C2F 0.28853900817779268f   //  0.2 * log2(e)
#define CWF -0.14426950408889634f  // -0.1 * log2(e)

// ---- init: Xs[p][i] = {x,y,z, -0.1*log2e*|x|^2} ----
__global__ __launch_bounds__(256) void init_k(const float* __restrict__ pc,
                                              const float* __restrict__ alphas,
                                              float* __restrict__ Xs) {
    int gid = blockIdx.x * 256 + threadIdx.x;
    if (gid >= NPAIR * NN) return;
    int p = gid >> 11;
    int i = gid & (NN - 1);
    int b = p >> 2, k = p & 3;
    const float* pcr = pc + ((size_t)b * NN + i) * 3;
    const float* al  = alphas + k * 3;
    float x = pcr[0] * al[0];
    float y = pcr[1] * al[1];
    float z = pcr[2] * al[2];
    float4 o;
    o.x = x; o.y = y; o.z = z;
    o.w = CWF * (x * x + y * y + z * z);
    ((float4*)Xs)[gid] = o;
}

// w(i,j) = exp2(xi.w + xj.w + C2F*dot); thresholded at 0.1
__device__ __forceinline__ float wfun(float4 xi, float4 xj) {
    float dot = xi.x * xj.x + xi.y * xj.y + xi.z * xj.z;
    float w = __builtin_amdgcn_exp2f((xi.w + xj.w) + C2F * dot);
    return (w < 0.1f) ? 0.0f : w;
}

// ---- deg: ihd[p][i] = 0.5 / deg. 128 rows/block, LDS-staged xj ----
__global__ __launch_bounds__(1024, 4) void deg_k(const float* __restrict__ Xs,
                                                 float* __restrict__ ihd) {
    __shared__ __align__(16) float smem[4096];   // stage 16x256 / red 16x128
    const int p    = blockIdx.y;
    const int tid  = threadIdx.x;
    const int lane = tid & 63;
    const int wv   = tid >> 6;
    const int rA   = blockIdx.x * 128 + lane;
    const int rB   = rA + 64;
    const float* Xp = Xs + (size_t)p * NN * 4;
    float4 xiA = *(const float4*)(Xp + rA * 4);
    float4 xiB = *(const float4*)(Xp + rB * 4);
    float sA = 0.f, sB = 0.f;
    float* stw = smem + wv * 256;                // 64 j x 4 floats
    const int jch = wv * 128;
    float4 v = *(const float4*)(Xp + (jch + lane) * 4);
    for (int jt = 0; jt < 2; ++jt) {
        *(float4*)(stw + lane * 4) = v;
        if (jt == 0) v = *(const float4*)(Xp + (jch + 64 + lane) * 4);
        __builtin_amdgcn_wave_barrier();
#pragma unroll 8
        for (int jj = 0; jj < 64; ++jj) {
            float4 xj = *(const float4*)(stw + jj * 4);
            sA += wfun(xiA, xj);
            sB += wfun(xiB, xj);
        }
        __builtin_amdgcn_wave_barrier();
    }
    __syncthreads();
    smem[wv * 128 + lane]      = sA;
    smem[wv * 128 + 64 + lane] = sB;
    __syncthreads();
    if (tid < 128) {
        float d = 0.f;
#pragma unroll
        for (int w = 0; w < 16; ++w) d += smem[w * 128 + tid];
        ihd[p * NN + blockIdx.x * 128 + tid] = 0.5f / d;
    }
}

// ---- fused apply: out = 0.5*cur + ihd[i]*(W@cur). W = 4 or 12 ----
// 16 waves x 128-j chunks; 2 rows/lane; per-wave LDS tiles of 256 floats.
template<int W>
__global__ __launch_bounds__(1024, 4) void apply_k(const float* __restrict__ Xs,
                                                   const float* __restrict__ ihd,
                                                   const float* __restrict__ cur,
                                                   float* __restrict__ out) {
    constexpr int E     = 4 + W;                 // floats per staged j entry
    constexpr int PARTS = E / 4;                 // f4 parts per entry
    constexpr int JT    = 256 / E;               // j per tile (16 or 32)
    constexpr int NT    = 128 / JT;              // tiles per wave
    constexpr int RS    = (W == 12) ? 13 : 4;    // red row stride (13: odd, conflict-free)
    constexpr int SMSZ  = (16 * 64 * RS > 4096) ? 16 * 64 * RS : 4096;
    __shared__ __align__(16) float smem[SMSZ];

    const int p    = blockIdx.y;
    const int tid  = threadIdx.x;
    const int lane = tid & 63;
    const int wv   = tid >> 6;
    const int rA   = blockIdx.x * 128 + lane;
    const int rB   = rA + 64;

    const float* Xp   = Xs  + (size_t)p * NN * 4;
    const float* curf = cur + (size_t)p * NN * W;
    float*       outf = out + (size_t)p * NN * W;
    const float* ihp  = ihd + p * NN;

    float4 xiA = *(const float4*)(Xp + rA * 4);
    float4 xiB = *(const float4*)(Xp + rB * 4);

    float accA[W], accB[W];
#pragma unroll
    for (int c = 0; c < W; ++c) { accA[c] = 0.f; accB[c] = 0.f; }

    float* stw = smem + wv * 256;
    const int jj0  = lane / PARTS;
    const int part = lane % PARTS;
    const int jch  = wv * 128;

    auto gload = [&](int jt) {
        int j = jch + jt * JT + jj0;
        const float* g = (part == 0) ? (Xp + j * 4)
                                     : (curf + (size_t)j * W + (part - 1) * 4);
        return *(const float4*)g;
    };

    float4 v = gload(0);
    for (int jt = 0; jt < NT; ++jt) {
        *(float4*)(stw + lane * 4) = v;          // byte offset lane*16: linear
        if (jt + 1 < NT) v = gload(jt + 1);      // prefetch next tile
        __builtin_amdgcn_wave_barrier();
#pragma unroll 4
        for (int jj = 0; jj < JT; ++jj) {
            const float* st = stw + jj * E;
            float4 xj = *(const float4*)st;      // uniform b128 broadcast
            float dA = xiA.x * xj.x + xiA.y * xj.y + xiA.z * xj.z;
            float dB = xiB.x * xj.x + xiB.y * xj.y + xiB.z * xj.z;
            float wA = __builtin_amdgcn_exp2f((xiA.w + xj.w) + C2F * dA);
            float wB = __builtin_amdgcn_exp2f((xiB.w + xj.w) + C2F * dB);
            wA = (wA < 0.1f) ? 0.f : wA;
            wB = (wB < 0.1f) ? 0.f : wB;
#pragma unroll
            for (int vv = 0; vv < W / 4; ++vv) {
                float4 cv = *(const float4*)(st + 4 + vv * 4);
                accA[vv * 4 + 0] += wA * cv.x;  accB[vv * 4 + 0] += wB * cv.x;
                accA[vv * 4 + 1] += wA * cv.y;  accB[vv * 4 + 1] += wB * cv.y;
                accA[vv * 4 + 2] += wA * cv.z;  accB[vv * 4 + 2] += wB * cv.z;
                accA[vv * 4 + 3] += wA * cv.w;  accB[vv * 4 + 3] += wB * cv.w;
            }
        }
        __builtin_amdgcn_wave_barrier();
    }

    // two-pass cross-wave reduce + store (red aliased over staging area)
    auto flush = [&](const float (&acc)[W], int pass) {
        __syncthreads();
#pragma unroll
        for (int c = 0; c < W; ++c) smem[wv * 64 * RS + lane * RS + c] = acc[c];
        __syncthreads();
        if (tid < 64 * W) {
            int r = tid / W, c = tid - r * W;
            float s = 0.f;
#pragma unroll
            for (int w = 0; w < 16; ++w) s += smem[w * 64 * RS + r * RS + c];
            int row = blockIdx.x * 128 + pass * 64 + r;
            outf[(size_t)row * W + c] = 0.5f * curf[(size_t)row * W + c] + ihp[row] * s;
        }
    };
    flush(accA, 0);
    flush(accB, 1);
}

// ---- build U (first 12 cols of first-order scattering) ----
__global__ __launch_bounds__(256) void buildU_k(const float* __restrict__ Xs,
                                                const float* __restrict__ L1b,
                                                float* __restrict__ U) {
    int gid = blockIdx.x * 256 + threadIdx.x;
    if (gid >= NPAIR * NN) return;
    float4 xr = ((const float4*)Xs)[gid];
    float prev0 = xr.x, prev1 = xr.y, prev2 = xr.z;
    float* urow = U + (size_t)gid * 12;
#pragma unroll
    for (int j = 0; j < 4; ++j) {
        float4 nx = ((const float4*)(L1b + (size_t)j * S4))[gid];
        urow[3 * j + 0] = fabsf(prev0 - nx.x);
        urow[3 * j + 1] = fabsf(prev1 - nx.y);
        urow[3 * j + 2] = fabsf(prev2 - nx.z);
        prev0 = nx.x; prev1 = nx.y; prev2 = nx.z;
    }
}

// ---- final mean over N of 48 features ----
__global__ __launch_bounds__(64) void reduce_k(const float* __restrict__ Xs,
                                               const float* __restrict__ L1b,
                                               const float* __restrict__ L2b,
                                               float* __restrict__ out) {
    const int f = blockIdx.x;
    const int p = blockIdx.y;
    const int lane = threadIdx.x;
    float s = 0.0f;
    for (int r = lane; r < NN; r += 64) {
        int pi = p * NN + r;
        float v;
        if (f < 3) {
            v = L1b[(size_t)4 * S4 + (size_t)pi * 4 + f];
        } else if (f < 18) {
            int j = (f - 3) / 3, c = (f - 3) % 3;
            float a = (j == 0) ? Xs[(size_t)pi * 4 + c]
                               : L1b[(size_t)(j - 1) * S4 + (size_t)pi * 4 + c];
            float b = L1b[(size_t)j * S4 + (size_t)pi * 4 + c];
            v = fabsf(a - b);
        } else {
            int g = f - 18;
            int j2, c;
            if (g < 3)       { j2 = 1; c = g; }
            else if (g < 9)  { j2 = 2; c = g - 3; }
            else if (g < 18) { j2 = 3; c = g - 9; }
            else             { j2 = 4; c = g - 18; }
            size_t idx = (size_t)pi * 12 + c;
            float a = L2b[(size_t)(j2 - 1) * S12 + idx];
            float b = L2b[(size_t)j2 * S12 + idx];
            v = fabsf(a - b);
        }
        s += v;
    }
#pragma unroll
    for (int off = 32; off > 0; off >>= 1) s += __shfl_down(s, off, 64);
    if (lane == 0) out[p * 48 + f] = s * (1.0f / 2048.0f);
}

extern "C" void kernel_launch(void* const* d_in, const int* in_sizes, int n_in,
                              void* d_out, int out_size, void* d_ws, size_t ws_size,
                              hipStream_t stream) {
    const float* pc     = (const float*)d_in[0];
    const float* alphas = (const float*)d_in[1];
    float* outp = (float*)d_out;

    float* w = (float*)d_ws;
    float* Xs  = w;               w += S4;
    float* ihd = w;               w += NPAIR * NN;
    float* sA  = w;               w += S4;
    float* sB  = w;               w += S4;
    float* L1b = w;               w += 5 * S4;
    float* U   = w;               w += S12;
    float* sC  = w;               w += S12;
    float* sD  = w;               w += S12;
    float* L2b = w;               w += 5 * S12;

    dim3 gridRows(NN / 128, NPAIR);   // 16 x 16 = 256 blocks (1/CU)

    init_k<<<dim3((NPAIR * NN) / 256), 256, 0, stream>>>(pc, alphas, Xs);
    deg_k<<<gridRows, 1024, 0, stream>>>(Xs, ihd);

    // bank 1: width 4 (xyz + diffused weight-term pad col)
    {
        const float* cur = Xs;
        int slot = 0;
        for (int step = 1; step <= 16; ++step) {
            bool sv = (step == 1 || step == 2 || step == 4 || step == 8 || step == 16);
            float* o = sv ? (L1b + (size_t)slot * S4)
                          : ((cur == sA) ? sB : sA);
            apply_k<4><<<gridRows, 1024, 0, stream>>>(Xs, ihd, cur, o);
            if (sv) ++slot;
            cur = o;
        }
    }

    buildU_k<<<dim3((NPAIR * NN) / 256), 256, 0, stream>>>(Xs, L1b, U);

    // bank 2: width 12
    {
        const float* cur = U;
        int slot = 0;
        for (int step = 1; step <= 16; ++step) {
            bool sv = (step == 1 || step == 2 || step == 4 || step == 8 || step == 16);
            float* o = sv ? (L2b + (size_t)slot * S12)
                          : ((cur == sC) ? sD : sC);
            apply_k<12><<<gridRows, 1024, 0, stream>>>(Xs, ihd, cur, o);
            if (sv) ++slot;
            cur = o;
        }
    }

    reduce_k<<<dim3(48, NPAIR), 64, 0, stream>>>(Xs, L1b, L2b, outp);
}

// Round 4
// 1096.548 us; speedup vs baseline: 2.9864x; 1.0123x over previous
//
#include <hip/hip_runtime.h>
#include <hip/hip_bf16.h>

// PointCloudNetPersistencePrediction — round 4: materialize A in fp16, MFMA.
// R3 post-mortem: VALU-bound on 32x recompute of exp2 affinities (63% VALUBusy,
// 19us ideal VALU floor per wide apply). Fix: A = 0.5I + ihd.W built ONCE
// (fp16, 8MB/pair, L3-resident), each apply = skinny GEMM via
// v_mfma_f32_16x16x32_f16. Error: fp16 rounding averages over 2048-wide dots
// (~1e-5/step). cur kept transposed [16][2048] fp16 so B-frags are contiguous.

#define NN 2048
#define NPAIR 16

typedef _Float16 half8 __attribute__((ext_vector_type(8)));
typedef _Float16 half4 __attribute__((ext_vector_type(4)));
typedef float f32x4 __attribute__((ext_vector_type(4)));

#define C2F 0.28853900817779268f   //  0.2 * log2(e)
#define CWF -0.14426950408889634f  // -0.1 * log2(e)

// ---- init: Xs fp32 [p][i][{x,y,z,q}]; XT fp16 [p][16][2048] (rows 3-15 = 0) ----
__global__ __launch_bounds__(256) void init_k(const float* __restrict__ pc,
                                              const float* __restrict__ alphas,
                                              float* __restrict__ Xs,
                                              _Float16* __restrict__ XT) {
    int gid = blockIdx.x * 256 + threadIdx.x;
    if (gid >= NPAIR * NN) return;
    int p = gid >> 11, i = gid & (NN - 1);
    int b = p >> 2, k = p & 3;
    const float* pcr = pc + ((size_t)b * NN + i) * 3;
    const float* al  = alphas + k * 3;
    float x = pcr[0] * al[0], y = pcr[1] * al[1], z = pcr[2] * al[2];
    float4 o; o.x = x; o.y = y; o.z = z; o.w = CWF * (x * x + y * y + z * z);
    ((float4*)Xs)[gid] = o;
    _Float16* xt = XT + (size_t)p * 16 * NN + i;
    xt[0 * NN] = (_Float16)x;
    xt[1 * NN] = (_Float16)y;
    xt[2 * NN] = (_Float16)z;
#pragma unroll
    for (int n = 3; n < 16; ++n) xt[n * NN] = (_Float16)0.f;
}

__device__ __forceinline__ float wfun(float4 xi, float4 xj) {
    float dot = xi.x * xj.x + xi.y * xj.y + xi.z * xj.z;
    float w = __builtin_amdgcn_exp2f((xi.w + xj.w) + C2F * dot);
    return (w < 0.1f) ? 0.0f : w;
}

// ---- deg: ihd[p][i] = 0.5 / deg (R3 structure, LDS-staged xj) ----
__global__ __launch_bounds__(1024, 4) void deg_k(const float* __restrict__ Xs,
                                                 float* __restrict__ ihd) {
    __shared__ __align__(16) float smem[4096];
    const int p    = blockIdx.y;
    const int tid  = threadIdx.x;
    const int lane = tid & 63;
    const int wv   = tid >> 6;
    const int rA   = blockIdx.x * 128 + lane;
    const int rB   = rA + 64;
    const float* Xp = Xs + (size_t)p * NN * 4;
    float4 xiA = *(const float4*)(Xp + rA * 4);
    float4 xiB = *(const float4*)(Xp + rB * 4);
    float sA = 0.f, sB = 0.f;
    float* stw = smem + wv * 256;
    const int jch = wv * 128;
    float4 v = *(const float4*)(Xp + (jch + lane) * 4);
    for (int jt = 0; jt < 2; ++jt) {
        *(float4*)(stw + lane * 4) = v;
        if (jt == 0) v = *(const float4*)(Xp + (jch + 64 + lane) * 4);
        __builtin_amdgcn_wave_barrier();
#pragma unroll 8
        for (int jj = 0; jj < 64; ++jj) {
            float4 xj = *(const float4*)(stw + jj * 4);
            sA += wfun(xiA, xj);
            sB += wfun(xiB, xj);
        }
        __builtin_amdgcn_wave_barrier();
    }
    __syncthreads();
    smem[wv * 128 + lane]      = sA;
    smem[wv * 128 + 64 + lane] = sB;
    __syncthreads();
    if (tid < 128) {
        float d = 0.f;
#pragma unroll
        for (int w = 0; w < 16; ++w) d += smem[w * 128 + tid];
        ihd[p * NN + blockIdx.x * 128 + tid] = 0.5f / d;
    }
}

// ---- build A fp16 [g][2048][2048]: A[i][j] = ihd[i]*w(i,j), diag = 0.5+ihd ----
__global__ __launch_bounds__(1024) void buildA_k(const float* __restrict__ Xs,
                                                 const float* __restrict__ ihd,
                                                 _Float16* __restrict__ A, int pair0) {
    int g = blockIdx.y, p = pair0 + g;
    int wv = threadIdx.x >> 6, lane = threadIdx.x & 63;
    const float4* Xp = (const float4*)(Xs + (size_t)p * NN * 4);
    _Float16* Ag = A + (size_t)g * NN * NN;
    int row0 = blockIdx.x * 128 + wv * 8;
    for (int rr = 0; rr < 8; ++rr) {
        int row = row0 + rr;
        float4 xi = Xp[row];                 // wave-uniform -> scalar load
        float ih = ihd[p * NN + row];
        float dia = 0.5f + ih;
        for (int jc = 0; jc < NN; jc += 64) {
            int j = jc + lane;
            float4 xj = Xp[j];               // coalesced, L1-resident (32KB/pair)
            float dot = xi.x * xj.x + xi.y * xj.y + xi.z * xj.z;
            float w = __builtin_amdgcn_exp2f((xi.w + xj.w) + C2F * dot);
            float a = (w < 0.1f) ? 0.f : (ih * w);
            if (j == row) a = dia;
            Ag[(size_t)row * NN + j] = (_Float16)a;
        }
    }
}

// ---- apply: Ct[16][2048] = (A @ Bt^T)^T via mfma 16x16x32 f16 ----
// wave = one 16-row M-tile; K swept 0..2047 in 32-steps; frags 16B contiguous.
__global__ __launch_bounds__(256) void mfma_apply_k(const _Float16* __restrict__ A,
                                                    const _Float16* __restrict__ Bt,
                                                    _Float16* __restrict__ Ct,
                                                    float* __restrict__ lvl,
                                                    int t, int pair0) {
    int wv = threadIdx.x >> 6, lane = threadIdx.x & 63;
    int g = blockIdx.y, p = pair0 + g;
    int m0 = (blockIdx.x * 4 + wv) * 16;
    int idx16 = lane & 15, quad = lane >> 4;
    const _Float16* ap = A  + (size_t)g * NN * NN + (size_t)(m0 + idx16) * NN + quad * 8;
    const _Float16* bp = Bt + ((size_t)p * 16 + idx16) * NN + quad * 8;
    f32x4 acc0 = {0.f, 0.f, 0.f, 0.f}, acc1 = {0.f, 0.f, 0.f, 0.f};
#pragma unroll 8
    for (int ks = 0; ks < 64; ks += 2) {
        half8 a0 = *(const half8*)(ap + ks * 32);
        half8 b0 = *(const half8*)(bp + ks * 32);
        acc0 = __builtin_amdgcn_mfma_f32_16x16x32_f16(a0, b0, acc0, 0, 0, 0);
        half8 a1 = *(const half8*)(ap + ks * 32 + 32);
        half8 b1 = *(const half8*)(bp + ks * 32 + 32);
        acc1 = __builtin_amdgcn_mfma_f32_16x16x32_f16(a1, b1, acc1, 0, 0, 0);
    }
    f32x4 acc = acc0 + acc1;
    int mrow = m0 + quad * 4;                // D: col=lane&15, row=quad*4+reg
    half4 h;
    h[0] = (_Float16)acc[0]; h[1] = (_Float16)acc[1];
    h[2] = (_Float16)acc[2]; h[3] = (_Float16)acc[3];
    *(half4*)(Ct + ((size_t)p * 16 + idx16) * NN + mrow) = h;
    if (lvl) {
        *(f32x4*)(lvl + (((size_t)p * 5 + t) * 16 + idx16) * NN + mrow) = acc;
    }
}

// ---- build UT fp16 [p][16][2048]: rows 0-11 = |psi_0..3 X|, 12-15 = 0 ----
__global__ __launch_bounds__(256) void buildU_k(const float* __restrict__ Xs,
                                                const float* __restrict__ LT1,
                                                _Float16* __restrict__ UT, int pair0) {
    int g = blockIdx.y, p = pair0 + g;
    int m = blockIdx.x * 256 + threadIdx.x;
    const float* lp = LT1 + (size_t)p * 5 * 16 * NN;
    float4 xr = ((const float4*)Xs)[p * NN + m];
    float prev[3] = {xr.x, xr.y, xr.z};
    _Float16* ut = UT + (size_t)p * 16 * NN + m;
#pragma unroll
    for (int jw = 0; jw < 4; ++jw) {
#pragma unroll
        for (int c = 0; c < 3; ++c) {
            float nx = lp[((size_t)jw * 16 + c) * NN + m];
            ut[(3 * jw + c) * NN] = (_Float16)fabsf(prev[c] - nx);
            prev[c] = nx;
        }
    }
#pragma unroll
    for (int n = 12; n < 16; ++n) ut[n * NN] = (_Float16)0.f;
}

// ---- final mean over N of 48 features (levels now [p][t][n][m]) ----
__global__ __launch_bounds__(64) void reduce_k(const float* __restrict__ Xs,
                                               const float* __restrict__ LT1,
                                               const float* __restrict__ LT2,
                                               float* __restrict__ out) {
    int f = blockIdx.x, p = blockIdx.y, lane = threadIdx.x;
    const float* l1 = LT1 + (size_t)p * 5 * 16 * NN;
    const float* l2 = LT2 + (size_t)p * 5 * 16 * NN;
    float s = 0.f;
    for (int m = lane; m < NN; m += 64) {
        float v;
        if (f < 3) {
            v = l1[((size_t)4 * 16 + f) * NN + m];        // low = P^16 X
        } else if (f < 18) {
            int j = (f - 3) / 3, c = (f - 3) % 3;
            float a = (j == 0) ? Xs[((size_t)p * NN + m) * 4 + c]
                               : l1[((size_t)(j - 1) * 16 + c) * NN + m];
            float b = l1[((size_t)j * 16 + c) * NN + m];
            v = fabsf(a - b);
        } else {
            int gg = f - 18, j2, uc;
            if (gg < 3)       { j2 = 1; uc = gg; }
            else if (gg < 9)  { j2 = 2; uc = gg - 3; }
            else if (gg < 18) { j2 = 3; uc = gg - 9; }
            else              { j2 = 4; uc = gg - 18; }
            v = fabsf(l2[((size_t)(j2 - 1) * 16 + uc) * NN + m]
                    - l2[((size_t)j2 * 16 + uc) * NN + m]);
        }
        s += v;
    }
#pragma unroll
    for (int off = 32; off > 0; off >>= 1) s += __shfl_down(s, off, 64);
    if (lane == 0) out[p * 48 + f] = s * (1.0f / NN);
}

extern "C" void kernel_launch(void* const* d_in, const int* in_sizes, int n_in,
                              void* d_out, int out_size, void* d_ws, size_t ws_size,
                              hipStream_t stream) {
    const float* pc     = (const float*)d_in[0];
    const float* alphas = (const float*)d_in[1];
    float* outp = (float*)d_out;

    char* base = (char*)d_ws;
    size_t off = 0;
    auto carve = [&](size_t bytes) -> void* {
        void* r = base + off;
        off = (off + bytes + 255) & ~(size_t)255;
        return r;
    };
    float*     Xs  = (float*)carve((size_t)NPAIR * NN * 4 * sizeof(float));
    float*     ihd = (float*)carve((size_t)NPAIR * NN * sizeof(float));
    _Float16*  XT  = (_Float16*)carve((size_t)NPAIR * 16 * NN * 2);
    _Float16*  UT  = (_Float16*)carve((size_t)NPAIR * 16 * NN * 2);
    _Float16*  pA  = (_Float16*)carve((size_t)NPAIR * 16 * NN * 2);
    _Float16*  pB  = (_Float16*)carve((size_t)NPAIR * 16 * NN * 2);
    float*     LT1 = (float*)carve((size_t)NPAIR * 5 * 16 * NN * sizeof(float));
    float*     LT2 = (float*)carve((size_t)NPAIR * 5 * 16 * NN * sizeof(float));
    size_t fixed = off;
    size_t Aper = (size_t)NN * NN * 2;       // 8 MB fp16 per pair
    int G = 16;
    while (G > 1 && fixed + (size_t)G * Aper > ws_size) G >>= 1;
    _Float16* A = (_Float16*)carve((size_t)G * Aper);

    init_k<<<dim3((NPAIR * NN) / 256), 256, 0, stream>>>(pc, alphas, Xs, XT);
    deg_k<<<dim3(NN / 128, NPAIR), 1024, 0, stream>>>(Xs, ihd);

    for (int p0 = 0; p0 < NPAIR; p0 += G) {
        buildA_k<<<dim3(NN / 128, G), 1024, 0, stream>>>(Xs, ihd, A, p0);

        // bank 1: B = XT
        {
            const _Float16* cur = XT;
            int slot = 0;
            for (int step = 1; step <= 16; ++step) {
                bool sv = (step == 1 || step == 2 || step == 4 || step == 8 || step == 16);
                _Float16* o = (cur == pA) ? pB : pA;
                mfma_apply_k<<<dim3(NN / 64, G), 256, 0, stream>>>(
                    A, cur, o, sv ? LT1 : nullptr, slot, p0);
                if (sv) ++slot;
                cur = o;
            }
        }

        buildU_k<<<dim3(NN / 256, G), 256, 0, stream>>>(Xs, LT1, UT, p0);

        // bank 2: B = UT
        {
            const _Float16* cur = UT;
            int slot = 0;
            for (int step = 1; step <= 16; ++step) {
                bool sv = (step == 1 || step == 2 || step == 4 || step == 8 || step == 16);
                _Float16* o = (cur == pA) ? pB : pA;
                mfma_apply_k<<<dim3(NN / 64, G), 256, 0, stream>>>(
                    A, cur, o, sv ? LT2 : nullptr, slot, p0);
                if (sv) ++slot;
                cur = o;
            }
        }
    }

    reduce_k<<<dim3(48, NPAIR), 64, 0, stream>>>(Xs, LT1, LT2, outp);
}